// Round 3
// baseline (623.210 us; speedup 1.0000x reference)
//
#include <hip/hip_runtime.h>
#include <math.h>

// Problem constants
#define B_  4
#define L_  2048
#define D_  1024
#define H_  16
#define HD_ 64

typedef __attribute__((ext_vector_type(8))) short short8;
typedef __attribute__((ext_vector_type(4))) float f32x4;

// fp32 -> bf16 bits, round-to-nearest-even
__device__ static inline unsigned short f2bf(float f) {
    union { float f; unsigned int u; } v; v.f = f;
    const unsigned int u = v.u;
    return (unsigned short)((u + 0x7FFFu + ((u >> 16) & 1u)) >> 16);
}

// packed fp32x2 -> bf16x2 (single VALU op; T12 primitive)
__device__ static inline unsigned cvt_pk_bf16(float a, float b) {
    unsigned r;
    asm("v_cvt_pk_bf16_f32 %0, %1, %2" : "=v"(r) : "v"(a), "v"(b));
    return r;
}

__device__ static inline void async_copy16(const void* g, void* lds)
{
    __builtin_amdgcn_global_load_lds(
        (const __attribute__((address_space(1))) void*)g,
        (__attribute__((address_space(3))) void*)lds, 16, 0, 0);
}

// ---------------------------------------------------------------------------
// fp32 -> bf16 convert, 8 elem/thread, 3 tensors in one launch (y selects)
// ---------------------------------------------------------------------------
__global__ __launch_bounds__(256) void cvt3_bf16_kernel(
    const float* __restrict__ i0, const float* __restrict__ i1,
    const float* __restrict__ i2,
    unsigned short* __restrict__ o0, unsigned short* __restrict__ o1,
    unsigned short* __restrict__ o2)
{
    const float* in = blockIdx.y == 0 ? i0 : blockIdx.y == 1 ? i1 : i2;
    unsigned short* out = blockIdx.y == 0 ? o0 : blockIdx.y == 1 ? o1 : o2;
    const size_t i = ((size_t)blockIdx.x * 256 + threadIdx.x) * 8;
    const float4 x = *(const float4*)&in[i];
    const float4 y = *(const float4*)&in[i + 4];
    ushort4 a0, a1;
    a0.x = f2bf(x.x); a0.y = f2bf(x.y); a0.z = f2bf(x.z); a0.w = f2bf(x.w);
    a1.x = f2bf(y.x); a1.y = f2bf(y.y); a1.z = f2bf(y.z); a1.w = f2bf(y.w);
    *(ushort4*)&out[i]     = a0;
    *(ushort4*)&out[i + 4] = a1;
}

// ---------------------------------------------------------------------------
// Transpose + convert: WT[n][k] = bf16(W[k][n]), square N=1024
// ---------------------------------------------------------------------------
__global__ __launch_bounds__(256) void transpose_bf16_kernel(
    const float* __restrict__ W, unsigned short* __restrict__ WT)
{
    __shared__ float t[32][33];
    const int c  = threadIdx.x & 31;
    const int r8 = threadIdx.x >> 5;          // 0..7
    const int k0 = blockIdx.y * 32;
    const int n0 = blockIdx.x * 32;
    #pragma unroll
    for (int i = 0; i < 4; ++i) {
        const int r = r8 + i * 8;
        t[r][c] = W[(size_t)(k0 + r) * 1024 + n0 + c];
    }
    __syncthreads();
    #pragma unroll
    for (int i = 0; i < 4; ++i) {
        const int r = r8 + i * 8;
        WT[(size_t)(n0 + r) * 1024 + k0 + c] = f2bf(t[c][r]);
    }
}

// 3 weight transposes in one launch (z selects)
__global__ __launch_bounds__(256) void trans3_bf16_kernel(
    const float* __restrict__ W0, const float* __restrict__ W1,
    const float* __restrict__ W2,
    unsigned short* __restrict__ T0, unsigned short* __restrict__ T1,
    unsigned short* __restrict__ T2)
{
    __shared__ float t[32][33];
    const float* W = blockIdx.z == 0 ? W0 : blockIdx.z == 1 ? W1 : W2;
    unsigned short* WT = blockIdx.z == 0 ? T0 : blockIdx.z == 1 ? T1 : T2;
    const int c  = threadIdx.x & 31;
    const int r8 = threadIdx.x >> 5;
    const int k0 = blockIdx.y * 32;
    const int n0 = blockIdx.x * 32;
    #pragma unroll
    for (int i = 0; i < 4; ++i) {
        const int r = r8 + i * 8;
        t[r][c] = W[(size_t)(k0 + r) * 1024 + n0 + c];
    }
    __syncthreads();
    #pragma unroll
    for (int i = 0; i < 4; ++i) {
        const int r = r8 + i * 8;
        WT[(size_t)(n0 + r) * 1024 + k0 + c] = f2bf(t[c][r]);
    }
}

// ---------------------------------------------------------------------------
// V transpose (bf16 in): Vb bf16 [B,L,D] -> vtb bf16 [B,H,HD,L]
// ---------------------------------------------------------------------------
__global__ __launch_bounds__(256) void vtrans_bf16_kernel(
    const unsigned short* __restrict__ Vb, unsigned short* __restrict__ vtb)
{
    __shared__ unsigned short t[64][68];
    const int tid = threadIdx.x;
    const int l0  = blockIdx.x * 64;
    const int h   = blockIdx.y;
    const int b   = blockIdx.z;
    const int rr  = tid >> 4;          // 0..15
    const int c4  = (tid & 15) * 4;
    #pragma unroll
    for (int i = 0; i < 4; ++i) {
        const int r = i * 16 + rr;
        *(ushort4*)&t[r][c4] =
            *(const ushort4*)&Vb[((size_t)(b * L_ + l0 + r)) * D_ + h * 64 + c4];
    }
    __syncthreads();
    #pragma unroll
    for (int i = 0; i < 4; ++i) {
        const int d = i * 16 + rr;
        ushort4 o;
        o.x = t[c4 + 0][d]; o.y = t[c4 + 1][d];
        o.z = t[c4 + 2][d]; o.w = t[c4 + 3][d];
        *(ushort4*)&vtb[((size_t)((b * H_ + h) * 64 + d)) * L_ + l0 + c4] = o;
    }
}

// ---------------------------------------------------------------------------
// Pack mask -> per-(query, quad) 16-bit words:
// mbt[((b*32 + kt)*2048 + q)*4 + Q] bit (kr*4+r) = mask key kt*64+kr*16+Q*4+r
// ---------------------------------------------------------------------------
__global__ __launch_bounds__(256) void pack_mask16_kernel(
    const int* __restrict__ mask, unsigned short* __restrict__ mbt)
{
    const unsigned g = blockIdx.x * 256 + threadIdx.x;
    const int v = mask[g];
    const unsigned long long bm = __ballot(v != 0);
    const int lane = threadIdx.x & 63;
    if (lane < 4) {
        const int b  = g >> 22;
        const int q  = (g >> 11) & 2047;
        const int kt = (g >> 6) & 31;
        unsigned long long x = (bm >> (4 * lane)) & 0x000F000F000F000FULL;
        x |= x >> 12;
        x |= x >> 24;
        mbt[((size_t)(b * 32 + kt) * 2048 + q) * 4 + lane] =
            (unsigned short)(x & 0xFFFFu);
    }
}

// ---------------------------------------------------------------------------
// bf16 MFMA GEMM body (m97 recipe), shared by the two GEMM kernels below.
// ---------------------------------------------------------------------------
template<int OUT_BF16>
__device__ static inline void gemm_body(
    const unsigned short* __restrict__ A, const unsigned short* __restrict__ WT,
    const float* __restrict__ bias, void* __restrict__ Cv,
    int M, int N, int K, float omul,
    unsigned short* At, unsigned short* Bt)
{
    const int tid  = threadIdx.x;
    const int lane = tid & 63;
    const int wave = tid >> 6;
    const int wm   = wave >> 1;
    const int wn   = wave & 1;
    const int quad = lane >> 4;
    const int l15  = lane & 15;
    const int m0   = blockIdx.y * 128;
    const int n0   = blockIdx.x * 128;

    f32x4 acc[4][4];
    #pragma unroll
    for (int i = 0; i < 4; ++i)
        #pragma unroll
        for (int j = 0; j < 4; ++j) acc[i][j] = (f32x4)0.f;

    for (int k0 = 0; k0 < K; k0 += 64) {
        __syncthreads();
        #pragma unroll
        for (int i = 0; i < 4; ++i) {
            const int fb  = i * 256 + wave * 64;
            const int f   = fb + lane;
            const int row = f >> 3;
            const int c8  = f & 7;
            async_copy16(&A [(size_t)(m0 + row) * K + k0 + c8 * 8],
                         (char*)At + (size_t)fb * 16);
            async_copy16(&WT[(size_t)(n0 + row) * K + k0 + c8 * 8],
                         (char*)Bt + (size_t)fb * 16);
        }
        __syncthreads();

        #pragma unroll
        for (int kk = 0; kk < 64; kk += 32) {
            short8 afr[4], bfr[4];
            #pragma unroll
            for (int mt = 0; mt < 4; ++mt)
                afr[mt] = *(const short8*)&At[(size_t)(wm * 64 + mt * 16 + l15) * 64 + kk + quad * 8];
            #pragma unroll
            for (int nt = 0; nt < 4; ++nt)
                bfr[nt] = *(const short8*)&Bt[(size_t)(wn * 64 + nt * 16 + l15) * 64 + kk + quad * 8];
            __builtin_amdgcn_s_setprio(1);
            #pragma unroll
            for (int mt = 0; mt < 4; ++mt)
                #pragma unroll
                for (int nt = 0; nt < 4; ++nt)
                    acc[mt][nt] = __builtin_amdgcn_mfma_f32_16x16x32_bf16(
                        afr[mt], bfr[nt], acc[mt][nt], 0, 0, 0);
            __builtin_amdgcn_s_setprio(0);
        }
    }

    #pragma unroll
    for (int nt = 0; nt < 4; ++nt) {
        const int col = n0 + wn * 64 + nt * 16 + l15;
        const float bv = bias[col];
        #pragma unroll
        for (int mt = 0; mt < 4; ++mt) {
            const int r0 = m0 + wm * 64 + mt * 16 + quad * 4;
            #pragma unroll
            for (int r = 0; r < 4; ++r) {
                const float val = (acc[mt][nt][r] + bv) * omul;
                if constexpr (OUT_BF16)
                    ((unsigned short*)Cv)[(size_t)(r0 + r) * N + col] = f2bf(val);
                else
                    ((float*)Cv)[(size_t)(r0 + r) * N + col] = val;
            }
        }
    }
}

// Q/K/V projections in ONE launch (z selects); bf16 out.
__global__ __launch_bounds__(256) void gemm3_mfma_kernel(
    const unsigned short* __restrict__ A0, const unsigned short* __restrict__ A1,
    const unsigned short* __restrict__ A2,
    const unsigned short* __restrict__ W0, const unsigned short* __restrict__ W1,
    const unsigned short* __restrict__ W2,
    const float* __restrict__ b0, const float* __restrict__ b1,
    const float* __restrict__ b2,
    unsigned short* __restrict__ C0, unsigned short* __restrict__ C1,
    unsigned short* __restrict__ C2, float om0)
{
    __shared__ __align__(16) unsigned short At[128 * 64];
    __shared__ __align__(16) unsigned short Bt[128 * 64];
    const int z = blockIdx.z;
    const unsigned short* A  = z == 0 ? A0 : z == 1 ? A1 : A2;
    const unsigned short* WT = z == 0 ? W0 : z == 1 ? W1 : W2;
    const float* bias        = z == 0 ? b0 : z == 1 ? b1 : b2;
    unsigned short* C        = z == 0 ? C0 : z == 1 ? C1 : C2;
    const float omul         = z == 0 ? om0 : 1.f;
    gemm_body<1>(A, WT, bias, C, B_ * L_, D_, D_, omul, At, Bt);
}

// Single GEMM, fp32 out (final projection)
__global__ __launch_bounds__(256) void gemm_mfma_kernel(
    const unsigned short* __restrict__ A, const unsigned short* __restrict__ WT,
    const float* __restrict__ bias, float* __restrict__ C,
    int M, int N, int K)
{
    __shared__ __align__(16) unsigned short At[128 * 64];
    __shared__ __align__(16) unsigned short Bt[128 * 64];
    gemm_body<0>(A, WT, bias, C, M, N, K, 1.f, At, Bt);
}

// ---------------------------------------------------------------------------
// MFMA flash attention, transposed orientation.
// - Q pre-scaled by 0.125*log2e (folded into Q-GEMM epilogue).
// - Kt/Vs LDS XOR-swizzled (T2, rule 21): linear LDS placement,
//   inv-swizzled source column chunk, swizzled ds_read.
// - T14 reg-split staging on a SINGLE K/V buffer: issue global_load_dwordx4
//   -> VGPRs at tile top (latency hides under compute), ds_write after the
//   read-complete barrier. LDS = 36KB -> 4 blocks/CU (16 waves), grid is
//   exactly 4 blocks/CU -> no occupancy tail (R2: tail was ~half the time).
// - T1: XCD-chunked block swizzle (K/V panel set per XCD = 4MB = one L2).
// - T5: setprio around MFMA clusters.
// ---------------------------------------------------------------------------
#define AQ 128
#define AK 64
#define PSTR 72   // Pt row stride (bf16): 144B = 16B-aligned, low-conflict
#define NT (L_ / AK)

__global__ __launch_bounds__(256, 4) void attn_mfma_kernel(
    const unsigned short* __restrict__ Qb,
    const unsigned short* __restrict__ Kb,
    const unsigned short* __restrict__ Vtg,
    const unsigned short* __restrict__ mbt,
    unsigned short* __restrict__ Cb)
{
    __shared__ __align__(16) unsigned short Kt[AK * 64];      // 8KB swz
    __shared__ __align__(16) unsigned short Vs[64 * AK];      // 8KB swz
    __shared__ __align__(16) unsigned short Pt[AQ * PSTR];    // 18KB
    __shared__ __align__(16) unsigned short Mt[2][AQ * 4];    // 2 x 1KB

    const int tid  = threadIdx.x;
    const int lane = tid & 63;
    const int w    = tid >> 6;          // wave 0..3: queries w*32..+31
    const int quad = lane >> 4;
    const int l15  = lane & 15;

    // XCD-chunked bijective swizzle (1024 wgs, 8 XCDs, 128/chunk)
    const int nid = (blockIdx.x & 7) * 128 + (blockIdx.x >> 3);
    const int q0  = (nid & 15) * AQ;
    const int h   = (nid >> 4) & 15;
    const int b   = nid >> 8;

    // global base pointers (loop-invariant)
    const unsigned short* kbase = &Kb [((size_t)(b * L_)) * D_ + h * 64];
    const unsigned short* vbase = &Vtg[((size_t)((b * H_ + h) * 64)) * L_];
    const unsigned short* mbase = &mbt[((size_t)(b * 32) * 2048 + q0) * 4];

    // per-wave staging geometry (same layout as global_load_lds scheme)
    // i in {0,1}: f = i*256 + w*64 + lane; row r = f>>3; chunk cs = (f&7)^(r&7)
    int srow[2], scol[2], sf[2];
    #pragma unroll
    for (int i = 0; i < 2; ++i) {
        const int f = i * 256 + w * 64 + lane;
        sf[i]   = f;
        srow[i] = f >> 3;
        scol[i] = ((f & 7) ^ ((f >> 3) & 7)) * 8;
    }

    // Q fragments (B-operand): [qc][kc], resident in VGPRs (pre-scaled)
    short8 qf[2][2];
    #pragma unroll
    for (int qc = 0; qc < 2; ++qc)
        #pragma unroll
        for (int kc = 0; kc < 2; ++kc)
            qf[qc][kc] = *(const short8*)
                &Qb[((size_t)(b * L_ + q0 + w * 32 + qc * 16 + l15)) * D_
                    + h * 64 + kc * 32 + quad * 8];

    f32x4 ot[4][2];                     // ctx^T acc: [d-tile][q-tile]
    #pragma unroll
    for (int dr = 0; dr < 4; ++dr)
        #pragma unroll
        for (int qc = 0; qc < 2; ++qc) ot[dr][qc] = (f32x4)0.f;
    float m_run[2] = {-INFINITY, -INFINITY};
    float l_run[2] = {0.f, 0.f};

    // prologue: tile 0 straight to LDS via async copy (latency exposed once)
    #pragma unroll
    for (int i = 0; i < 2; ++i) {
        async_copy16(&kbase[(size_t)srow[i] * D_ + scol[i]],
                     (char*)Kt + sf[i] / 64 * 1024 + (sf[i] & 63) * 16);
        async_copy16(&vbase[(size_t)srow[i] * L_ + scol[i]],
                     (char*)Vs + sf[i] / 64 * 1024 + (sf[i] & 63) * 16);
    }
    if (w == 3)
        async_copy16(&mbase[lane * 8], (char*)&Mt[0][0]);
    __syncthreads();   // implicit vmcnt(0) drain: tile 0 ready

    for (int kt = 0; kt < NT; ++kt) {
        const int cur = kt & 1;

        // T14 issue-early: next tile's K/V -> VGPRs; mask -> Mt[cur^1] async
        short8 kstg[2], vstg[2];
        if (kt + 1 < NT) {
            const int k1 = (kt + 1) * AK;
            #pragma unroll
            for (int i = 0; i < 2; ++i) {
                kstg[i] = *(const short8*)&kbase[(size_t)(k1 + srow[i]) * D_ + scol[i]];
                vstg[i] = *(const short8*)&vbase[(size_t)srow[i] * L_ + k1 + scol[i]];
            }
            if (w == 3)
                async_copy16(&mbase[(size_t)(kt + 1) * 2048 * 4 + lane * 8],
                             (char*)&Mt[cur ^ 1][0]);
        }

        // ---- S^T = K·Q^T : st[key-tile][q-tile] -------------------------
        f32x4 st[4][2];
        {
            short8 kf[4];
            #pragma unroll
            for (int kr = 0; kr < 4; ++kr)
                kf[kr] = *(const short8*)
                    &Kt[(kr * 16 + l15) * 64 + ((quad ^ (l15 & 7)) * 8)];
            __builtin_amdgcn_s_setprio(1);
            #pragma unroll
            for (int kr = 0; kr < 4; ++kr)
                #pragma unroll
                for (int qc = 0; qc < 2; ++qc)
                    st[kr][qc] = __builtin_amdgcn_mfma_f32_16x16x32_bf16(
                        kf[kr], qf[qc][0], (f32x4)0.f, 0, 0, 0);
            __builtin_amdgcn_s_setprio(0);
        }
        {
            short8 kf[4];
            #pragma unroll
            for (int kr = 0; kr < 4; ++kr)
                kf[kr] = *(const short8*)
                    &Kt[(kr * 16 + l15) * 64 + (((4 + quad) ^ (l15 & 7)) * 8)];
            __builtin_amdgcn_s_setprio(1);
            #pragma unroll
            for (int kr = 0; kr < 4; ++kr)
                #pragma unroll
                for (int qc = 0; qc < 2; ++qc)
                    st[kr][qc] = __builtin_amdgcn_mfma_f32_16x16x32_bf16(
                        kf[kr], qf[qc][1], st[kr][qc], 0, 0, 0);
            __builtin_amdgcn_s_setprio(0);
        }

        // ---- online softmax (per-lane per query) + P write --------------
        #pragma unroll
        for (int qc = 0; qc < 2; ++qc) {
            const unsigned m16 = Mt[cur][(w * 32 + qc * 16 + l15) * 4 + quad];
            float rmax = -INFINITY;
            #pragma unroll
            for (int kr = 0; kr < 4; ++kr) {
                const unsigned nib = (m16 >> (kr * 4)) & 0xFu;
                #pragma unroll
                for (int r = 0; r < 4; ++r) {
                    const float x = ((nib >> r) & 1u) ? st[kr][qc][r] : -INFINITY;
                    st[kr][qc][r] = x;
                    rmax = fmaxf(rmax, x);
                }
            }
            rmax = fmaxf(rmax, __shfl_xor(rmax, 16));
            rmax = fmaxf(rmax, __shfl_xor(rmax, 32));
            // T13 defer-max: skip rescale unless max grew by > 8 (exp2 dom)
            if (__any(rmax > m_run[qc] + 8.f)) {
                const float mnew  = fmaxf(m_run[qc], rmax);
                const float msafe = fmaxf(mnew, -1e30f);
                const float alpha = exp2f(m_run[qc] - msafe);
                l_run[qc] *= alpha;
                #pragma unroll
                for (int dr = 0; dr < 4; ++dr) {
                    ot[dr][qc][0] *= alpha; ot[dr][qc][1] *= alpha;
                    ot[dr][qc][2] *= alpha; ot[dr][qc][3] *= alpha;
                }
                m_run[qc] = mnew;
            }
            const float msafe = fmaxf(m_run[qc], -1e30f);
            float psum = 0.f;
            #pragma unroll
            for (int kr = 0; kr < 4; ++kr) {
                const float p0 = exp2f(st[kr][qc][0] - msafe);
                const float p1 = exp2f(st[kr][qc][1] - msafe);
                const float p2 = exp2f(st[kr][qc][2] - msafe);
                const float p3 = exp2f(st[kr][qc][3] - msafe);
                psum += (p0 + p1) + (p2 + p3);
                uint2 pk;
                pk.x = cvt_pk_bf16(p0, p1);
                pk.y = cvt_pk_bf16(p2, p3);
                *(uint2*)&Pt[(w * 32 + qc * 16 + l15) * PSTR + kr * 16 + quad * 4] = pk;
            }
            psum += __shfl_xor(psum, 16);
            psum += __shfl_xor(psum, 32);
            l_run[qc] += psum;
        }

        // ---- ctx^T += V^T · P^T  (Pt is wave-private; no barrier needed) -
        #pragma unroll
        for (int kc = 0; kc < 2; ++kc) {
            short8 vf[4], pf[2];
            #pragma unroll
            for (int dr = 0; dr < 4; ++dr)
                vf[dr] = *(const short8*)
                    &Vs[(dr * 16 + l15) * 64 + (((kc * 4 + quad) ^ (l15 & 7)) * 8)];
            #pragma unroll
            for (int qc = 0; qc < 2; ++qc)
                pf[qc] = *(const short8*)&Pt[(w * 32 + qc * 16 + l15) * PSTR
                                             + kc * 32 + quad * 8];
            __builtin_amdgcn_s_setprio(1);
            #pragma unroll
            for (int dr = 0; dr < 4; ++dr)
                #pragma unroll
                for (int qc = 0; qc < 2; ++qc)
                    ot[dr][qc] = __builtin_amdgcn_mfma_f32_16x16x32_bf16(
                        vf[dr], pf[qc], ot[dr][qc], 0, 0, 0);
            __builtin_amdgcn_s_setprio(0);
        }

        // T14 write-late: publish next tile into the single K/V buffer.
        // barrier 1: all waves done READING Kt/Vs for tile kt
        // barrier 2: next tile's ds_writes visible to all waves
        if (kt + 1 < NT) {
            __syncthreads();
            #pragma unroll
            for (int i = 0; i < 2; ++i) {
                *(short8*)((char*)Kt + sf[i] * 16) = kstg[i];
                *(short8*)((char*)Vs + sf[i] * 16) = vstg[i];
            }
            __syncthreads();
        }
    }

    // ---- epilogue: normalize, store ctx as bf16 [B,L,D] -----------------
    #pragma unroll
    for (int qc = 0; qc < 2; ++qc) {
        const float rinv = (l_run[qc] > 0.f) ? (1.f / l_run[qc]) : 0.f;
        const size_t base = ((size_t)(b * L_ + q0 + w * 32 + qc * 16 + l15)) * D_
                            + h * 64;
        #pragma unroll
        for (int dr = 0; dr < 4; ++dr) {
            ushort4 o;
            o.x = f2bf(ot[dr][qc][0] * rinv);
            o.y = f2bf(ot[dr][qc][1] * rinv);
            o.z = f2bf(ot[dr][qc][2] * rinv);
            o.w = f2bf(ot[dr][qc][3] * rinv);
            *(ushort4*)&Cb[base + dr * 16 + quad * 4] = o;
        }
    }
}

// ---------------------------------------------------------------------------
extern "C" void kernel_launch(void* const* d_in, const int* in_sizes, int n_in,
                              void* d_out, int out_size, void* d_ws, size_t ws_size,
                              hipStream_t stream)
{
    const float* q    = (const float*)d_in[0];
    const float* k    = (const float*)d_in[1];
    const float* v    = (const float*)d_in[2];
    const int*   mask = (const int*)d_in[3];
    const float* WQ   = (const float*)d_in[4];
    const float* bQ   = (const float*)d_in[5];
    const float* WK   = (const float*)d_in[6];
    const float* bK   = (const float*)d_in[7];
    const float* WV   = (const float*)d_in[8];
    const float* bV   = (const float*)d_in[9];
    const float* WO   = (const float*)d_in[10];
    const float* bO   = (const float*)d_in[11];
    float* out = (float*)d_out;

    const size_t NTOK = (size_t)B_ * L_;        // 8192

    // ws map (128 MiB): 8 x 16MB bf16 zones
    char* W = (char*)d_ws;
    unsigned short* qin = (unsigned short*)(W);                        // 16MB
    unsigned short* kin = (unsigned short*)(W + ((size_t)16  << 20));  // 16MB
    unsigned short* vin = (unsigned short*)(W + ((size_t)32  << 20));  // 16MB
    unsigned short* qbf = (unsigned short*)(W + ((size_t)48  << 20));  // 16MB
    unsigned short* kbf = (unsigned short*)(W + ((size_t)64  << 20));  // 16MB
    unsigned short* vbf = (unsigned short*)(W + ((size_t)80  << 20));  // 16MB
    unsigned short* vtb = (unsigned short*)(W + ((size_t)96  << 20));  // 16MB
    unsigned short* cb  = (unsigned short*)(W + ((size_t)112 << 20));  // 16MB
    // WTo reuses vin zone (dead after the fused QKV GEMM); must live in ws,
    // NOT d_out, because the final GEMM writes out over all of d_out.
    unsigned short* WTo = vin;

    // d_out as scratch until final GEMM (all dead before the out-write):
    unsigned short* mbt16 = (unsigned short*)d_out;                          // 2MB
    unsigned short* WTq = (unsigned short*)((char*)d_out + ((size_t)2 << 20));
    unsigned short* WTk = (unsigned short*)((char*)d_out + ((size_t)4 << 20));
    unsigned short* WTv = (unsigned short*)((char*)d_out + ((size_t)6 << 20));

    pack_mask16_kernel<<<(B_ * L_ * L_) / 256, 256, 0, stream>>>(mask, mbt16);

    const int cvtg = (int)(NTOK * D_ / (256 * 8));   // 4096
    cvt3_bf16_kernel<<<dim3(cvtg, 3), 256, 0, stream>>>(q, k, v, qin, kin, vin);

    trans3_bf16_kernel<<<dim3(32, 32, 3), 256, 0, stream>>>(
        WQ, WK, WV, WTq, WTk, WTv);

    // Projections, bf16 out, one launch. Q gets scale*log2e folded in.
    const float qscale = 0.125f * 1.44269504088896340736f;
    dim3 ggrd3(D_ / 128, NTOK / 128, 3);        // (8, 64, 3) = 1536 wgs
    gemm3_mfma_kernel<<<ggrd3, 256, 0, stream>>>(
        qin, kin, vin, WTq, WTk, WTv, bQ, bK, bV, qbf, kbf, vbf, qscale);

    // WO transpose into vin zone (dead now); V transpose to [B,H,HD,L]
    transpose_bf16_kernel<<<dim3(32, 32), 256, 0, stream>>>(WO, WTo);
    vtrans_bf16_kernel<<<dim3(L_ / 64, H_, B_), 256, 0, stream>>>(vbf, vtb);

    attn_mfma_kernel<<<dim3(1024), 256, 0, stream>>>(qbf, kbf, vtb, mbt16, cb);

    dim3 ggrd(D_ / 128, NTOK / 128);            // (8, 64)
    gemm_mfma_kernel<<<ggrd, 256, 0, stream>>>(cb, WTo, bO, out, (int)NTOK, D_, D_);
}

// Round 5
// 500.198 us; speedup vs baseline: 1.2459x; 1.2459x over previous
//
#include <hip/hip_runtime.h>
#include <math.h>

// Problem constants
#define B_  4
#define L_  2048
#define D_  1024
#define H_  16
#define HD_ 64

typedef __attribute__((ext_vector_type(8))) short short8;
typedef __attribute__((ext_vector_type(4))) float f32x4;
typedef __attribute__((ext_vector_type(4))) int   i32x4;

// fp32 -> bf16 bits, round-to-nearest-even
__device__ static inline unsigned short f2bf(float f) {
    union { float f; unsigned int u; } v; v.f = f;
    const unsigned int u = v.u;
    return (unsigned short)((u + 0x7FFFu + ((u >> 16) & 1u)) >> 16);
}

// packed fp32x2 -> bf16x2 (single VALU op; T12 primitive)
__device__ static inline unsigned cvt_pk_bf16(float a, float b) {
    unsigned r;
    asm("v_cvt_pk_bf16_f32 %0, %1, %2" : "=v"(r) : "v"(a), "v"(b));
    return r;
}

__device__ static inline void async_copy16(const void* g, void* lds)
{
    __builtin_amdgcn_global_load_lds(
        (const __attribute__((address_space(1))) void*)g,
        (__attribute__((address_space(3))) void*)lds, 16, 0, 0);
}

// ---------------------------------------------------------------------------
// fp32 -> bf16 convert, 8 elem/thread, 3 tensors in one launch (y selects)
// ---------------------------------------------------------------------------
__global__ __launch_bounds__(256) void cvt3_bf16_kernel(
    const float* __restrict__ i0, const float* __restrict__ i1,
    const float* __restrict__ i2,
    unsigned short* __restrict__ o0, unsigned short* __restrict__ o1,
    unsigned short* __restrict__ o2)
{
    const float* in = blockIdx.y == 0 ? i0 : blockIdx.y == 1 ? i1 : i2;
    unsigned short* out = blockIdx.y == 0 ? o0 : blockIdx.y == 1 ? o1 : o2;
    const size_t i = ((size_t)blockIdx.x * 256 + threadIdx.x) * 8;
    const float4 x = *(const float4*)&in[i];
    const float4 y = *(const float4*)&in[i + 4];
    ushort4 a0, a1;
    a0.x = f2bf(x.x); a0.y = f2bf(x.y); a0.z = f2bf(x.z); a0.w = f2bf(x.w);
    a1.x = f2bf(y.x); a1.y = f2bf(y.y); a1.z = f2bf(y.z); a1.w = f2bf(y.w);
    *(ushort4*)&out[i]     = a0;
    *(ushort4*)&out[i + 4] = a1;
}

// ---------------------------------------------------------------------------
// Transpose + convert: WT[n][k] = bf16(W[k][n]), square N=1024
// ---------------------------------------------------------------------------
__global__ __launch_bounds__(256) void transpose_bf16_kernel(
    const float* __restrict__ W, unsigned short* __restrict__ WT)
{
    __shared__ float t[32][33];
    const int c  = threadIdx.x & 31;
    const int r8 = threadIdx.x >> 5;          // 0..7
    const int k0 = blockIdx.y * 32;
    const int n0 = blockIdx.x * 32;
    #pragma unroll
    for (int i = 0; i < 4; ++i) {
        const int r = r8 + i * 8;
        t[r][c] = W[(size_t)(k0 + r) * 1024 + n0 + c];
    }
    __syncthreads();
    #pragma unroll
    for (int i = 0; i < 4; ++i) {
        const int r = r8 + i * 8;
        WT[(size_t)(n0 + r) * 1024 + k0 + c] = f2bf(t[c][r]);
    }
}

// 3 weight transposes in one launch (z selects)
__global__ __launch_bounds__(256) void trans3_bf16_kernel(
    const float* __restrict__ W0, const float* __restrict__ W1,
    const float* __restrict__ W2,
    unsigned short* __restrict__ T0, unsigned short* __restrict__ T1,
    unsigned short* __restrict__ T2)
{
    __shared__ float t[32][33];
    const float* W = blockIdx.z == 0 ? W0 : blockIdx.z == 1 ? W1 : W2;
    unsigned short* WT = blockIdx.z == 0 ? T0 : blockIdx.z == 1 ? T1 : T2;
    const int c  = threadIdx.x & 31;
    const int r8 = threadIdx.x >> 5;
    const int k0 = blockIdx.y * 32;
    const int n0 = blockIdx.x * 32;
    #pragma unroll
    for (int i = 0; i < 4; ++i) {
        const int r = r8 + i * 8;
        t[r][c] = W[(size_t)(k0 + r) * 1024 + n0 + c];
    }
    __syncthreads();
    #pragma unroll
    for (int i = 0; i < 4; ++i) {
        const int r = r8 + i * 8;
        WT[(size_t)(n0 + r) * 1024 + k0 + c] = f2bf(t[c][r]);
    }
}

// ---------------------------------------------------------------------------
// V transpose (bf16 in): Vb bf16 [B,L,D] -> vtb bf16 [B,H,HD,L]
// ---------------------------------------------------------------------------
__global__ __launch_bounds__(256) void vtrans_bf16_kernel(
    const unsigned short* __restrict__ Vb, unsigned short* __restrict__ vtb)
{
    __shared__ unsigned short t[64][68];
    const int tid = threadIdx.x;
    const int l0  = blockIdx.x * 64;
    const int h   = blockIdx.y;
    const int b   = blockIdx.z;
    const int rr  = tid >> 4;          // 0..15
    const int c4  = (tid & 15) * 4;
    #pragma unroll
    for (int i = 0; i < 4; ++i) {
        const int r = i * 16 + rr;
        *(ushort4*)&t[r][c4] =
            *(const ushort4*)&Vb[((size_t)(b * L_ + l0 + r)) * D_ + h * 64 + c4];
    }
    __syncthreads();
    #pragma unroll
    for (int i = 0; i < 4; ++i) {
        const int d = i * 16 + rr;
        ushort4 o;
        o.x = t[c4 + 0][d]; o.y = t[c4 + 1][d];
        o.z = t[c4 + 2][d]; o.w = t[c4 + 3][d];
        *(ushort4*)&vtb[((size_t)((b * H_ + h) * 64 + d)) * L_ + l0 + c4] = o;
    }
}

// ---------------------------------------------------------------------------
// Pack mask -> per-(query, quad) 16-bit words:
// mbt[((b*32 + kt)*2048 + q)*4 + Q] bit (kr*4+r) = mask key kt*64+kr*16+Q*4+r
// ---------------------------------------------------------------------------
__global__ __launch_bounds__(256) void pack_mask16_kernel(
    const int* __restrict__ mask, unsigned short* __restrict__ mbt)
{
    const unsigned g = blockIdx.x * 256 + threadIdx.x;
    const int v = mask[g];
    const unsigned long long bm = __ballot(v != 0);
    const int lane = threadIdx.x & 63;
    if (lane < 4) {
        const int b  = g >> 22;
        const int q  = (g >> 11) & 2047;
        const int kt = (g >> 6) & 31;
        unsigned long long x = (bm >> (4 * lane)) & 0x000F000F000F000FULL;
        x |= x >> 12;
        x |= x >> 24;
        mbt[((size_t)(b * 32 + kt) * 2048 + q) * 4 + lane] =
            (unsigned short)(x & 0xFFFFu);
    }
}

// ---------------------------------------------------------------------------
// bf16 MFMA GEMM body (m97 recipe), shared by the two GEMM kernels below.
// ---------------------------------------------------------------------------
template<int OUT_BF16>
__device__ static inline void gemm_body(
    const unsigned short* __restrict__ A, const unsigned short* __restrict__ WT,
    const float* __restrict__ bias, void* __restrict__ Cv,
    int M, int N, int K, float omul,
    unsigned short* At, unsigned short* Bt)
{
    const int tid  = threadIdx.x;
    const int lane = tid & 63;
    const int wave = tid >> 6;
    const int wm   = wave >> 1;
    const int wn   = wave & 1;
    const int quad = lane >> 4;
    const int l15  = lane & 15;
    const int m0   = blockIdx.y * 128;
    const int n0   = blockIdx.x * 128;

    f32x4 acc[4][4];
    #pragma unroll
    for (int i = 0; i < 4; ++i)
        #pragma unroll
        for (int j = 0; j < 4; ++j) acc[i][j] = (f32x4)0.f;

    for (int k0 = 0; k0 < K; k0 += 64) {
        __syncthreads();
        #pragma unroll
        for (int i = 0; i < 4; ++i) {
            const int fb  = i * 256 + wave * 64;
            const int f   = fb + lane;
            const int row = f >> 3;
            const int c8  = f & 7;
            async_copy16(&A [(size_t)(m0 + row) * K + k0 + c8 * 8],
                         (char*)At + (size_t)fb * 16);
            async_copy16(&WT[(size_t)(n0 + row) * K + k0 + c8 * 8],
                         (char*)Bt + (size_t)fb * 16);
        }
        __syncthreads();

        #pragma unroll
        for (int kk = 0; kk < 64; kk += 32) {
            short8 afr[4], bfr[4];
            #pragma unroll
            for (int mt = 0; mt < 4; ++mt)
                afr[mt] = *(const short8*)&At[(size_t)(wm * 64 + mt * 16 + l15) * 64 + kk + quad * 8];
            #pragma unroll
            for (int nt = 0; nt < 4; ++nt)
                bfr[nt] = *(const short8*)&Bt[(size_t)(wn * 64 + nt * 16 + l15) * 64 + kk + quad * 8];
            __builtin_amdgcn_s_setprio(1);
            #pragma unroll
            for (int mt = 0; mt < 4; ++mt)
                #pragma unroll
                for (int nt = 0; nt < 4; ++nt)
                    acc[mt][nt] = __builtin_amdgcn_mfma_f32_16x16x32_bf16(
                        afr[mt], bfr[nt], acc[mt][nt], 0, 0, 0);
            __builtin_amdgcn_s_setprio(0);
        }
    }

    #pragma unroll
    for (int nt = 0; nt < 4; ++nt) {
        const int col = n0 + wn * 64 + nt * 16 + l15;
        const float bv = bias[col];
        #pragma unroll
        for (int mt = 0; mt < 4; ++mt) {
            const int r0 = m0 + wm * 64 + mt * 16 + quad * 4;
            #pragma unroll
            for (int r = 0; r < 4; ++r) {
                const float val = (acc[mt][nt][r] + bv) * omul;
                if constexpr (OUT_BF16)
                    ((unsigned short*)Cv)[(size_t)(r0 + r) * N + col] = f2bf(val);
                else
                    ((float*)Cv)[(size_t)(r0 + r) * N + col] = val;
            }
        }
    }
}

// Q/K/V projections in ONE launch (z selects); bf16 out.
__global__ __launch_bounds__(256) void gemm3_mfma_kernel(
    const unsigned short* __restrict__ A0, const unsigned short* __restrict__ A1,
    const unsigned short* __restrict__ A2,
    const unsigned short* __restrict__ W0, const unsigned short* __restrict__ W1,
    const unsigned short* __restrict__ W2,
    const float* __restrict__ b0, const float* __restrict__ b1,
    const float* __restrict__ b2,
    unsigned short* __restrict__ C0, unsigned short* __restrict__ C1,
    unsigned short* __restrict__ C2, float om0)
{
    __shared__ __align__(16) unsigned short At[128 * 64];
    __shared__ __align__(16) unsigned short Bt[128 * 64];
    const int z = blockIdx.z;
    const unsigned short* A  = z == 0 ? A0 : z == 1 ? A1 : A2;
    const unsigned short* WT = z == 0 ? W0 : z == 1 ? W1 : W2;
    const float* bias        = z == 0 ? b0 : z == 1 ? b1 : b2;
    unsigned short* C        = z == 0 ? C0 : z == 1 ? C1 : C2;
    const float omul         = z == 0 ? om0 : 1.f;
    gemm_body<1>(A, WT, bias, C, B_ * L_, D_, D_, omul, At, Bt);
}

// Single GEMM, fp32 out (final projection)
__global__ __launch_bounds__(256) void gemm_mfma_kernel(
    const unsigned short* __restrict__ A, const unsigned short* __restrict__ WT,
    const float* __restrict__ bias, float* __restrict__ C,
    int M, int N, int K)
{
    __shared__ __align__(16) unsigned short At[128 * 64];
    __shared__ __align__(16) unsigned short Bt[128 * 64];
    gemm_body<0>(A, WT, bias, C, M, N, K, 1.f, At, Bt);
}

// ---------------------------------------------------------------------------
// MFMA flash attention, transposed orientation.
// - Q pre-scaled by 0.125*log2e (folded into Q-GEMM epilogue).
// - Kt/Vs LDS XOR-swizzled (T2, rule 21): linear LDS placement,
//   inv-swizzled global source column chunk, swizzled ds_read.
// - R2's double-buffered global_load_lds staging, ONE barrier per tile.
// - Pt LDS eliminated: P redistribution done in-register. Shuffle BOTH
//   kr candidates (lo=pk[kc*2], hi=pk[kc*2+1]) from src lanes
//   ((quad&1)*32+l15, +16), then select on the DEST by quad&2
//   (R4 post-mortem: pre-shuffle select used the source lane's quad ->
//   wrong kr for dest quads 1,2).
//   LDS: 16+16+2 = 34KB -> 4 blocks/CU; grid = exactly 4/CU -> no tail.
// - T1 XCD-chunked swizzle; T5 setprio; T13 defer-max.
// ---------------------------------------------------------------------------
#define AQ 128
#define AK 64
#define NT (L_ / AK)

__global__ __launch_bounds__(256, 4) void attn_mfma_kernel(
    const unsigned short* __restrict__ Qb,
    const unsigned short* __restrict__ Kb,
    const unsigned short* __restrict__ Vtg,
    const unsigned short* __restrict__ mbt,
    unsigned short* __restrict__ Cb)
{
    __shared__ __align__(16) unsigned short Kt[2][AK * 64];   // 2 x 8KB swz
    __shared__ __align__(16) unsigned short Vs[2][64 * AK];   // 2 x 8KB swz
    __shared__ __align__(16) unsigned short Mt[2][AQ * 4];    // 2 x 1KB

    const int tid  = threadIdx.x;
    const int lane = tid & 63;
    const int w    = tid >> 6;          // wave 0..3: queries w*32..+31
    const int quad = lane >> 4;
    const int l15  = lane & 15;

    // XCD-chunked bijective swizzle (1024 wgs, 8 XCDs, 128/chunk)
    const int nid = (blockIdx.x & 7) * 128 + (blockIdx.x >> 3);
    const int q0  = (nid & 15) * AQ;
    const int h   = (nid >> 4) & 15;
    const int b   = nid >> 8;

    // global base pointers (loop-invariant)
    const unsigned short* kbase = &Kb [((size_t)(b * L_)) * D_ + h * 64];
    const unsigned short* vbase = &Vtg[((size_t)((b * H_ + h) * 64)) * L_];
    const unsigned short* mbase = &mbt[((size_t)(b * 32) * 2048 + q0) * 4];

    // Q fragments (B-operand): [qc][kc], resident in VGPRs (pre-scaled)
    short8 qf[2][2];
    #pragma unroll
    for (int qc = 0; qc < 2; ++qc)
        #pragma unroll
        for (int kc = 0; kc < 2; ++kc)
            qf[qc][kc] = *(const short8*)
                &Qb[((size_t)(b * L_ + q0 + w * 32 + qc * 16 + l15)) * D_
                    + h * 64 + kc * 32 + quad * 8];

    f32x4 ot[4][2];                     // ctx^T acc: [d-tile][q-tile]
    #pragma unroll
    for (int dr = 0; dr < 4; ++dr)
        #pragma unroll
        for (int qc = 0; qc < 2; ++qc) ot[dr][qc] = (f32x4)0.f;
    float m_run[2] = {-INFINITY, -INFINITY};
    float l_run[2] = {0.f, 0.f};

    // staging: issue async global->LDS for tile kt into buffer bi
    auto stage = [&](int bi, int kt) {
        const int k0 = kt * AK;
        #pragma unroll
        for (int i = 0; i < 2; ++i) {
            const int fb = i * 256 + w * 64;
            const int f  = fb + lane;
            const int r  = f >> 3;
            const int cs = (f & 7) ^ (r & 7);
            async_copy16(&kbase[(size_t)(k0 + r) * D_ + cs * 8],
                         (char*)&Kt[bi][0] + fb * 16);
            async_copy16(&vbase[(size_t)r * L_ + k0 + cs * 8],
                         (char*)&Vs[bi][0] + fb * 16);
        }
        if (w == 3)
            async_copy16(&mbase[(size_t)kt * 2048 * 4 + lane * 8],
                         (char*)&Mt[bi][0]);
    };

    stage(0, 0);
    __syncthreads();   // implicit vmcnt(0) drain: tile 0 ready

    // shuffle source lanes for P redistribution (kc- and kr-independent)
    const int srcA = ((quad & 1) << 5) + l15;
    const int srcB = srcA + 16;
    const bool selHi = (quad & 2) != 0;   // dest quads 2,3 take kr=kc*2+1

    for (int kt = 0; kt < NT; ++kt) {
        const int cur = kt & 1;
        if (kt + 1 < NT) stage(cur ^ 1, kt + 1);   // flies under compute

        // ---- S^T = K·Q^T : st[key-tile][q-tile] -------------------------
        f32x4 st[4][2];
        {
            short8 kf[4];
            #pragma unroll
            for (int kr = 0; kr < 4; ++kr)
                kf[kr] = *(const short8*)
                    &Kt[cur][(kr * 16 + l15) * 64 + ((quad ^ (l15 & 7)) * 8)];
            __builtin_amdgcn_s_setprio(1);
            #pragma unroll
            for (int kr = 0; kr < 4; ++kr)
                #pragma unroll
                for (int qc = 0; qc < 2; ++qc)
                    st[kr][qc] = __builtin_amdgcn_mfma_f32_16x16x32_bf16(
                        kf[kr], qf[qc][0], (f32x4)0.f, 0, 0, 0);
            __builtin_amdgcn_s_setprio(0);
        }
        {
            short8 kf[4];
            #pragma unroll
            for (int kr = 0; kr < 4; ++kr)
                kf[kr] = *(const short8*)
                    &Kt[cur][(kr * 16 + l15) * 64 + (((4 + quad) ^ (l15 & 7)) * 8)];
            __builtin_amdgcn_s_setprio(1);
            #pragma unroll
            for (int kr = 0; kr < 4; ++kr)
                #pragma unroll
                for (int qc = 0; qc < 2; ++qc)
                    st[kr][qc] = __builtin_amdgcn_mfma_f32_16x16x32_bf16(
                        kf[kr], qf[qc][1], st[kr][qc], 0, 0, 0);
            __builtin_amdgcn_s_setprio(0);
        }

        // ---- online softmax (per-lane per query); pack P into pk regs ----
        uint2 pk[2][4];   // [qc][kr] : 4 bf16 keys (quad*4+0..3 of kr block)
        #pragma unroll
        for (int qc = 0; qc < 2; ++qc) {
            const unsigned m16 = Mt[cur][(w * 32 + qc * 16 + l15) * 4 + quad];
            float rmax = -INFINITY;
            #pragma unroll
            for (int kr = 0; kr < 4; ++kr) {
                const unsigned nib = (m16 >> (kr * 4)) & 0xFu;
                #pragma unroll
                for (int r = 0; r < 4; ++r) {
                    const float x = ((nib >> r) & 1u) ? st[kr][qc][r] : -INFINITY;
                    st[kr][qc][r] = x;
                    rmax = fmaxf(rmax, x);
                }
            }
            rmax = fmaxf(rmax, __shfl_xor(rmax, 16));
            rmax = fmaxf(rmax, __shfl_xor(rmax, 32));
            // T13 defer-max: skip rescale unless max grew by > 8 (exp2 dom)
            if (__any(rmax > m_run[qc] + 8.f)) {
                const float mnew  = fmaxf(m_run[qc], rmax);
                const float msafe = fmaxf(mnew, -1e30f);
                const float alpha = exp2f(m_run[qc] - msafe);
                l_run[qc] *= alpha;
                #pragma unroll
                for (int dr = 0; dr < 4; ++dr) {
                    ot[dr][qc][0] *= alpha; ot[dr][qc][1] *= alpha;
                    ot[dr][qc][2] *= alpha; ot[dr][qc][3] *= alpha;
                }
                m_run[qc] = mnew;
            }
            const float msafe = fmaxf(m_run[qc], -1e30f);
            float psum = 0.f;
            #pragma unroll
            for (int kr = 0; kr < 4; ++kr) {
                const float p0 = exp2f(st[kr][qc][0] - msafe);
                const float p1 = exp2f(st[kr][qc][1] - msafe);
                const float p2 = exp2f(st[kr][qc][2] - msafe);
                const float p3 = exp2f(st[kr][qc][3] - msafe);
                psum += (p0 + p1) + (p2 + p3);
                pk[qc][kr].x = cvt_pk_bf16(p0, p1);
                pk[qc][kr].y = cvt_pk_bf16(p2, p3);
            }
            psum += __shfl_xor(psum, 16);
            psum += __shfl_xor(psum, 32);
            l_run[qc] += psum;
        }

        // ---- ctx^T += V^T · P^T ; P frag via shuffle-both + dest select --
        #pragma unroll
        for (int kc = 0; kc < 2; ++kc) {
            short8 vf[4], pf[2];
            #pragma unroll
            for (int dr = 0; dr < 4; ++dr)
                vf[dr] = *(const short8*)
                    &Vs[cur][(dr * 16 + l15) * 64 + (((kc * 4 + quad) ^ (l15 & 7)) * 8)];
            #pragma unroll
            for (int qc = 0; qc < 2; ++qc) {
                const uint2 lo = pk[qc][kc * 2];
                const uint2 hi = pk[qc][kc * 2 + 1];
                const int ax = __shfl((int)lo.x, srcA, 64);
                const int ay = __shfl((int)lo.y, srcA, 64);
                const int az = __shfl((int)lo.x, srcB, 64);
                const int aw = __shfl((int)lo.y, srcB, 64);
                const int bx = __shfl((int)hi.x, srcA, 64);
                const int by = __shfl((int)hi.y, srcA, 64);
                const int bz = __shfl((int)hi.x, srcB, 64);
                const int bw = __shfl((int)hi.y, srcB, 64);
                i32x4 t;
                t.x = selHi ? bx : ax;
                t.y = selHi ? by : ay;
                t.z = selHi ? bz : az;
                t.w = selHi ? bw : aw;
                pf[qc] = *reinterpret_cast<short8*>(&t);
            }
            __builtin_amdgcn_s_setprio(1);
            #pragma unroll
            for (int dr = 0; dr < 4; ++dr)
                #pragma unroll
                for (int qc = 0; qc < 2; ++qc)
                    ot[dr][qc] = __builtin_amdgcn_mfma_f32_16x16x32_bf16(
                        vf[dr], pf[qc], ot[dr][qc], 0, 0, 0);
            __builtin_amdgcn_s_setprio(0);
        }

        // one barrier/tile: drains next tile's loads and publishes
        // "all waves done reading buffer cur"
        __syncthreads();
    }

    // ---- epilogue: normalize, store ctx as bf16 [B,L,D] -----------------
    #pragma unroll
    for (int qc = 0; qc < 2; ++qc) {
        const float rinv = (l_run[qc] > 0.f) ? (1.f / l_run[qc]) : 0.f;
        const size_t base = ((size_t)(b * L_ + q0 + w * 32 + qc * 16 + l15)) * D_
                            + h * 64;
        #pragma unroll
        for (int dr = 0; dr < 4; ++dr) {
            ushort4 o;
            o.x = f2bf(ot[dr][qc][0] * rinv);
            o.y = f2bf(ot[dr][qc][1] * rinv);
            o.z = f2bf(ot[dr][qc][2] * rinv);
            o.w = f2bf(ot[dr][qc][3] * rinv);
            *(ushort4*)&Cb[base + dr * 16 + quad * 4] = o;
        }
    }
}

// ---------------------------------------------------------------------------
extern "C" void kernel_launch(void* const* d_in, const int* in_sizes, int n_in,
                              void* d_out, int out_size, void* d_ws, size_t ws_size,
                              hipStream_t stream)
{
    const float* q    = (const float*)d_in[0];
    const float* k    = (const float*)d_in[1];
    const float* v    = (const float*)d_in[2];
    const int*   mask = (const int*)d_in[3];
    const float* WQ   = (const float*)d_in[4];
    const float* bQ   = (const float*)d_in[5];
    const float* WK   = (const float*)d_in[6];
    const float* bK   = (const float*)d_in[7];
    const float* WV   = (const float*)d_in[8];
    const float* bV   = (const float*)d_in[9];
    const float* WO   = (const float*)d_in[10];
    const float* bO   = (const float*)d_in[11];
    float* out = (float*)d_out;

    const size_t NTOK = (size_t)B_ * L_;        // 8192

    // ws map (128 MiB): 8 x 16MB bf16 zones
    char* W = (char*)d_ws;
    unsigned short* qin = (unsigned short*)(W);                        // 16MB
    unsigned short* kin = (unsigned short*)(W + ((size_t)16  << 20));  // 16MB
    unsigned short* vin = (unsigned short*)(W + ((size_t)32  << 20));  // 16MB
    unsigned short* qbf = (unsigned short*)(W + ((size_t)48  << 20));  // 16MB
    unsigned short* kbf = (unsigned short*)(W + ((size_t)64  << 20));  // 16MB
    unsigned short* vbf = (unsigned short*)(W + ((size_t)80  << 20));  // 16MB
    unsigned short* vtb = (unsigned short*)(W + ((size_t)96  << 20));  // 16MB
    unsigned short* cb  = (unsigned short*)(W + ((size_t)112 << 20));  // 16MB
    // WTo reuses vin zone (dead after the fused QKV GEMM); must live in ws,
    // NOT d_out, because the final GEMM writes out over all of d_out.
    unsigned short* WTo = vin;

    // d_out as scratch until final GEMM (all dead before the out-write):
    unsigned short* mbt16 = (unsigned short*)d_out;                          // 2MB
    unsigned short* WTq = (unsigned short*)((char*)d_out + ((size_t)2 << 20));
    unsigned short* WTk = (unsigned short*)((char*)d_out + ((size_t)4 << 20));
    unsigned short* WTv = (unsigned short*)((char*)d_out + ((size_t)6 << 20));

    pack_mask16_kernel<<<(B_ * L_ * L_) / 256, 256, 0, stream>>>(mask, mbt16);

    const int cvtg = (int)(NTOK * D_ / (256 * 8));   // 4096
    cvt3_bf16_kernel<<<dim3(cvtg, 3), 256, 0, stream>>>(q, k, v, qin, kin, vin);

    trans3_bf16_kernel<<<dim3(32, 32, 3), 256, 0, stream>>>(
        WQ, WK, WV, WTq, WTk, WTv);

    // Projections, bf16 out, one launch. Q gets scale*log2e folded in.
    const float qscale = 0.125f * 1.44269504088896340736f;
    dim3 ggrd3(D_ / 128, NTOK / 128, 3);        // (8, 64, 3) = 1536 wgs
    gemm3_mfma_kernel<<<ggrd3, 256, 0, stream>>>(
        qin, kin, vin, WTq, WTk, WTv, bQ, bK, bV, qbf, kbf, vbf, qscale);

    // WO transpose into vin zone (dead now); V transpose to [B,H,HD,L]
    transpose_bf16_kernel<<<dim3(32, 32), 256, 0, stream>>>(WO, WTo);
    vtrans_bf16_kernel<<<dim3(L_ / 64, H_, B_), 256, 0, stream>>>(vbf, vtb);

    attn_mfma_kernel<<<dim3(1024), 256, 0, stream>>>(qbf, kbf, vtb, mbt16, cb);

    dim3 ggrd(D_ / 128, NTOK / 128);            // (8, 64)
    gemm_mfma_kernel<<<ggrd, 256, 0, stream>>>(cb, WTo, bO, out, (int)NTOK, D_, D_);
}

// Round 8
// 480.199 us; speedup vs baseline: 1.2978x; 1.0416x over previous
//
#include <hip/hip_runtime.h>
#include <math.h>

// Problem constants
#define B_  4
#define L_  2048
#define D_  1024
#define H_  16
#define HD_ 64

typedef __attribute__((ext_vector_type(8))) short short8;
typedef __attribute__((ext_vector_type(4))) float f32x4;
typedef __attribute__((ext_vector_type(16))) float f32x16;
typedef __attribute__((ext_vector_type(4))) int   i32x4;

// fp32 -> bf16 bits, round-to-nearest-even
__device__ static inline unsigned short f2bf(float f) {
    union { float f; unsigned int u; } v; v.f = f;
    const unsigned int u = v.u;
    return (unsigned short)((u + 0x7FFFu + ((u >> 16) & 1u)) >> 16);
}

// packed fp32x2 -> bf16x2 (single VALU op; T12 primitive)
__device__ static inline unsigned cvt_pk_bf16(float a, float b) {
    unsigned r;
    asm("v_cvt_pk_bf16_f32 %0, %1, %2" : "=v"(r) : "v"(a), "v"(b));
    return r;
}

__device__ static inline void async_copy16(const void* g, void* lds)
{
    __builtin_amdgcn_global_load_lds(
        (const __attribute__((address_space(1))) void*)g,
        (__attribute__((address_space(3))) void*)lds, 16, 0, 0);
}

// ---------------------------------------------------------------------------
// fp32 -> bf16 convert, 8 elem/thread, 3 tensors in one launch (y selects)
// ---------------------------------------------------------------------------
__global__ __launch_bounds__(256) void cvt3_bf16_kernel(
    const float* __restrict__ i0, const float* __restrict__ i1,
    const float* __restrict__ i2,
    unsigned short* __restrict__ o0, unsigned short* __restrict__ o1,
    unsigned short* __restrict__ o2)
{
    const float* in = blockIdx.y == 0 ? i0 : blockIdx.y == 1 ? i1 : i2;
    unsigned short* out = blockIdx.y == 0 ? o0 : blockIdx.y == 1 ? o1 : o2;
    const size_t i = ((size_t)blockIdx.x * 256 + threadIdx.x) * 8;
    const float4 x = *(const float4*)&in[i];
    const float4 y = *(const float4*)&in[i + 4];
    ushort4 a0, a1;
    a0.x = f2bf(x.x); a0.y = f2bf(x.y); a0.z = f2bf(x.z); a0.w = f2bf(x.w);
    a1.x = f2bf(y.x); a1.y = f2bf(y.y); a1.z = f2bf(y.z); a1.w = f2bf(y.w);
    *(ushort4*)&out[i]     = a0;
    *(ushort4*)&out[i + 4] = a1;
}

// ---------------------------------------------------------------------------
// Transpose + convert: WT[n][k] = bf16(W[k][n]), square N=1024
// ---------------------------------------------------------------------------
__global__ __launch_bounds__(256) void transpose_bf16_kernel(
    const float* __restrict__ W, unsigned short* __restrict__ WT)
{
    __shared__ float t[32][33];
    const int c  = threadIdx.x & 31;
    const int r8 = threadIdx.x >> 5;          // 0..7
    const int k0 = blockIdx.y * 32;
    const int n0 = blockIdx.x * 32;
    #pragma unroll
    for (int i = 0; i < 4; ++i) {
        const int r = r8 + i * 8;
        t[r][c] = W[(size_t)(k0 + r) * 1024 + n0 + c];
    }
    __syncthreads();
    #pragma unroll
    for (int i = 0; i < 4; ++i) {
        const int r = r8 + i * 8;
        WT[(size_t)(n0 + r) * 1024 + k0 + c] = f2bf(t[c][r]);
    }
}

// 3 weight transposes in one launch (z selects)
__global__ __launch_bounds__(256) void trans3_bf16_kernel(
    const float* __restrict__ W0, const float* __restrict__ W1,
    const float* __restrict__ W2,
    unsigned short* __restrict__ T0, unsigned short* __restrict__ T1,
    unsigned short* __restrict__ T2)
{
    __shared__ float t[32][33];
    const float* W = blockIdx.z == 0 ? W0 : blockIdx.z == 1 ? W1 : W2;
    unsigned short* WT = blockIdx.z == 0 ? T0 : blockIdx.z == 1 ? T1 : T2;
    const int c  = threadIdx.x & 31;
    const int r8 = threadIdx.x >> 5;
    const int k0 = blockIdx.y * 32;
    const int n0 = blockIdx.x * 32;
    #pragma unroll
    for (int i = 0; i < 4; ++i) {
        const int r = r8 + i * 8;
        t[r][c] = W[(size_t)(k0 + r) * 1024 + n0 + c];
    }
    __syncthreads();
    #pragma unroll
    for (int i = 0; i < 4; ++i) {
        const int r = r8 + i * 8;
        WT[(size_t)(n0 + r) * 1024 + k0 + c] = f2bf(t[c][r]);
    }
}

// ---------------------------------------------------------------------------
// V transpose (bf16 in): Vb bf16 [B,L,D] -> vtb bf16 [B,H,HD,L]
// ---------------------------------------------------------------------------
__global__ __launch_bounds__(256) void vtrans_bf16_kernel(
    const unsigned short* __restrict__ Vb, unsigned short* __restrict__ vtb)
{
    __shared__ unsigned short t[64][68];
    const int tid = threadIdx.x;
    const int l0  = blockIdx.x * 64;
    const int h   = blockIdx.y;
    const int b   = blockIdx.z;
    const int rr  = tid >> 4;          // 0..15
    const int c4  = (tid & 15) * 4;
    #pragma unroll
    for (int i = 0; i < 4; ++i) {
        const int r = i * 16 + rr;
        *(ushort4*)&t[r][c4] =
            *(const ushort4*)&Vb[((size_t)(b * L_ + l0 + r)) * D_ + h * 64 + c4];
    }
    __syncthreads();
    #pragma unroll
    for (int i = 0; i < 4; ++i) {
        const int d = i * 16 + rr;
        ushort4 o;
        o.x = t[c4 + 0][d]; o.y = t[c4 + 1][d];
        o.z = t[c4 + 2][d]; o.w = t[c4 + 3][d];
        *(ushort4*)&vtb[((size_t)((b * H_ + h) * 64 + d)) * L_ + l0 + c4] = o;
    }
}

// ---------------------------------------------------------------------------
// Pack mask -> key-tile-major 64-bit row words (as 2x uint32):
// mm[((b*32 + kt)*2048 + q)*2 + w] bit j = mask key kt*64 + w*32 + j
// ---------------------------------------------------------------------------
__global__ __launch_bounds__(256) void pack_mask32_kernel(
    const int* __restrict__ mask, unsigned int* __restrict__ mm)
{
    const unsigned g = blockIdx.x * 256 + threadIdx.x;
    const int v = mask[g];
    const unsigned long long bm = __ballot(v != 0);
    const int lane = threadIdx.x & 63;
    const int b = g >> 22;
    const int q = (g >> 11) & 2047;
    const int k = g & 2047;
    const unsigned idx = ((unsigned)(b * 32 + (k >> 6)) * 2048 + q) * 2 + ((k >> 5) & 1);
    if (lane == 0)       mm[idx] = (unsigned)bm;
    else if (lane == 32) mm[idx] = (unsigned)(bm >> 32);
}

// ---------------------------------------------------------------------------
// bf16 MFMA GEMM body (m97 recipe), shared by the two GEMM kernels below.
// ---------------------------------------------------------------------------
template<int OUT_BF16>
__device__ static inline void gemm_body(
    const unsigned short* __restrict__ A, const unsigned short* __restrict__ WT,
    const float* __restrict__ bias, void* __restrict__ Cv,
    int M, int N, int K, float omul,
    unsigned short* At, unsigned short* Bt)
{
    const int tid  = threadIdx.x;
    const int lane = tid & 63;
    const int wave = tid >> 6;
    const int wm   = wave >> 1;
    const int wn   = wave & 1;
    const int quad = lane >> 4;
    const int l15  = lane & 15;
    const int m0   = blockIdx.y * 128;
    const int n0   = blockIdx.x * 128;

    f32x4 acc[4][4];
    #pragma unroll
    for (int i = 0; i < 4; ++i)
        #pragma unroll
        for (int j = 0; j < 4; ++j) acc[i][j] = (f32x4)0.f;

    for (int k0 = 0; k0 < K; k0 += 64) {
        __syncthreads();
        #pragma unroll
        for (int i = 0; i < 4; ++i) {
            const int fb  = i * 256 + wave * 64;
            const int f   = fb + lane;
            const int row = f >> 3;
            const int c8  = f & 7;
            async_copy16(&A [(size_t)(m0 + row) * K + k0 + c8 * 8],
                         (char*)At + (size_t)fb * 16);
            async_copy16(&WT[(size_t)(n0 + row) * K + k0 + c8 * 8],
                         (char*)Bt + (size_t)fb * 16);
        }
        __syncthreads();

        #pragma unroll
        for (int kk = 0; kk < 64; kk += 32) {
            short8 afr[4], bfr[4];
            #pragma unroll
            for (int mt = 0; mt < 4; ++mt)
                afr[mt] = *(const short8*)&At[(size_t)(wm * 64 + mt * 16 + l15) * 64 + kk + quad * 8];
            #pragma unroll
            for (int nt = 0; nt < 4; ++nt)
                bfr[nt] = *(const short8*)&Bt[(size_t)(wn * 64 + nt * 16 + l15) * 64 + kk + quad * 8];
            __builtin_amdgcn_s_setprio(1);
            #pragma unroll
            for (int mt = 0; mt < 4; ++mt)
                #pragma unroll
                for (int nt = 0; nt < 4; ++nt)
                    acc[mt][nt] = __builtin_amdgcn_mfma_f32_16x16x32_bf16(
                        afr[mt], bfr[nt], acc[mt][nt], 0, 0, 0);
            __builtin_amdgcn_s_setprio(0);
        }
    }

    #pragma unroll
    for (int nt = 0; nt < 4; ++nt) {
        const int col = n0 + wn * 64 + nt * 16 + l15;
        const float bv = bias[col];
        #pragma unroll
        for (int mt = 0; mt < 4; ++mt) {
            const int r0 = m0 + wm * 64 + mt * 16 + quad * 4;
            #pragma unroll
            for (int r = 0; r < 4; ++r) {
                const float val = (acc[mt][nt][r] + bv) * omul;
                if constexpr (OUT_BF16)
                    ((unsigned short*)Cv)[(size_t)(r0 + r) * N + col] = f2bf(val);
                else
                    ((float*)Cv)[(size_t)(r0 + r) * N + col] = val;
            }
        }
    }
}

// Q/K/V projections in ONE launch (z selects); bf16 out.
__global__ __launch_bounds__(256) void gemm3_mfma_kernel(
    const unsigned short* __restrict__ A0, const unsigned short* __restrict__ A1,
    const unsigned short* __restrict__ A2,
    const unsigned short* __restrict__ W0, const unsigned short* __restrict__ W1,
    const unsigned short* __restrict__ W2,
    const float* __restrict__ b0, const float* __restrict__ b1,
    const float* __restrict__ b2,
    unsigned short* __restrict__ C0, unsigned short* __restrict__ C1,
    unsigned short* __restrict__ C2, float om0)
{
    __shared__ __align__(16) unsigned short At[128 * 64];
    __shared__ __align__(16) unsigned short Bt[128 * 64];
    const int z = blockIdx.z;
    const unsigned short* A  = z == 0 ? A0 : z == 1 ? A1 : A2;
    const unsigned short* WT = z == 0 ? W0 : z == 1 ? W1 : W2;
    const float* bias        = z == 0 ? b0 : z == 1 ? b1 : b2;
    unsigned short* C        = z == 0 ? C0 : z == 1 ? C1 : C2;
    const float omul         = z == 0 ? om0 : 1.f;
    gemm_body<1>(A, WT, bias, C, B_ * L_, D_, D_, omul, At, Bt);
}

// Single GEMM, fp32 out (final projection)
__global__ __launch_bounds__(256) void gemm_mfma_kernel(
    const unsigned short* __restrict__ A, const unsigned short* __restrict__ WT,
    const float* __restrict__ bias, float* __restrict__ C,
    int M, int N, int K)
{
    __shared__ __align__(16) unsigned short At[128 * 64];
    __shared__ __align__(16) unsigned short Bt[128 * 64];
    gemm_body<0>(A, WT, bias, C, M, N, K, 1.f, At, Bt);
}

// ---------------------------------------------------------------------------
// MFMA flash attention, 32x32x16 core.
// S^T[key][q] = K·Q^T; C/D: col=lane&31=q (one query/lane),
// row = (reg&3) + 8*(reg>>2) + 4*(lane>>5).
// Softmax per-lane + one shfl_xor(32).
// PV: O^T[d][q] = V^T·P^T. P^T B-frag built in-register with
// 4 cvt_pk + 4 shfl_xor(32) + 4 post-shuffle selects per k-step
// (R7 post-mortem: permlane32_swap direction unverifiable -> replaced by
// unambiguous shfl_xor; select on DEST side per R4 lesson).
// Staging/swizzle/XCD-chunk/dbuf identical to verified R5 pipeline.
// ---------------------------------------------------------------------------
#define AQ 128
#define AK 64
#define NT (L_ / AK)

__global__ __launch_bounds__(256, 4) void attn_mfma_kernel(
    const unsigned short* __restrict__ Qb,
    const unsigned short* __restrict__ Kb,
    const unsigned short* __restrict__ Vtg,
    const unsigned int* __restrict__ mbt,
    unsigned short* __restrict__ Cb)
{
    __shared__ __align__(16) unsigned short Kt[2][AK * 64];   // 2 x 8KB swz
    __shared__ __align__(16) unsigned short Vs[2][64 * AK];   // 2 x 8KB swz
    __shared__ __align__(16) unsigned int   Mt[2][AQ * 2];    // 2 x 1KB

    const int tid  = threadIdx.x;
    const int lane = tid & 63;
    const int w    = tid >> 6;          // wave 0..3: queries w*32..+31
    const int hi   = lane >> 5;         // half-lane
    const int l31  = lane & 31;

    // XCD-chunked bijective swizzle (1024 wgs, 8 XCDs, 128/chunk)
    const int nid = (blockIdx.x & 7) * 128 + (blockIdx.x >> 3);
    const int q0  = (nid & 15) * AQ;
    const int h   = (nid >> 4) & 15;
    const int b   = nid >> 8;

    // global base pointers (loop-invariant)
    const unsigned short* kbase = &Kb [((size_t)(b * L_)) * D_ + h * 64];
    const unsigned short* vbase = &Vtg[((size_t)((b * H_ + h) * 64)) * L_];
    const unsigned int*   mbase = &mbt[((size_t)(b * 32) * 2048 + q0) * 2];

    const int q = q0 + w * 32 + l31;    // this lane's query row

    // Q fragments (B-operand): qf[dstep] = Q[q][dstep*16 + hi*8 .. +7]
    short8 qf[4];
    #pragma unroll
    for (int ds = 0; ds < 4; ++ds)
        qf[ds] = *(const short8*)
            &Qb[((size_t)(b * L_ + q)) * D_ + h * 64 + ds * 16 + hi * 8];

    f32x16 ot[2];                       // O^T acc: [d-block (32 d each)]
    ot[0] = (f32x16)0.f; ot[1] = (f32x16)0.f;
    float m_run = -INFINITY, l_run = 0.f;

    const int swz = l31 & 7;            // read-side XOR for Kt/Vs chunks

    // staging: issue async global->LDS for tile kt into buffer bi
    auto stage = [&](int bi, int kt) {
        const int k0 = kt * AK;
        #pragma unroll
        for (int i = 0; i < 2; ++i) {
            const int fb = i * 256 + w * 64;
            const int f  = fb + lane;
            const int r  = f >> 3;
            const int cs = (f & 7) ^ (r & 7);
            async_copy16(&kbase[(size_t)(k0 + r) * D_ + cs * 8],
                         (char*)&Kt[bi][0] + fb * 16);
            async_copy16(&vbase[(size_t)r * L_ + k0 + cs * 8],
                         (char*)&Vs[bi][0] + fb * 16);
        }
        if (w == 3)
            async_copy16(&mbase[(size_t)kt * 2048 * 2 + lane * 4],
                         (char*)&Mt[bi][0]);
    };

    stage(0, 0);
    __syncthreads();   // implicit vmcnt(0) drain: tile 0 ready

    for (int kt = 0; kt < NT; ++kt) {
        const int cur = kt & 1;
        if (kt + 1 < NT) stage(cur ^ 1, kt + 1);   // flies under compute

        // ---- S^T = K·Q^T : st{kb} covers keys kb*32..+31 ----------------
        f32x16 st0, st1;
        {
            short8 kf0 = *(const short8*)
                &Kt[cur][(l31) * 64 + ((0 * 2 + hi) ^ swz) * 8];
            short8 kf1 = *(const short8*)
                &Kt[cur][(32 + l31) * 64 + ((0 * 2 + hi) ^ swz) * 8];
            __builtin_amdgcn_s_setprio(1);
            st0 = __builtin_amdgcn_mfma_f32_32x32x16_bf16(
                kf0, qf[0], (f32x16)0.f, 0, 0, 0);
            st1 = __builtin_amdgcn_mfma_f32_32x32x16_bf16(
                kf1, qf[0], (f32x16)0.f, 0, 0, 0);
            __builtin_amdgcn_s_setprio(0);
        }
        #pragma unroll
        for (int ds = 1; ds < 4; ++ds) {
            short8 kf0 = *(const short8*)
                &Kt[cur][(l31) * 64 + ((ds * 2 + hi) ^ swz) * 8];
            short8 kf1 = *(const short8*)
                &Kt[cur][(32 + l31) * 64 + ((ds * 2 + hi) ^ swz) * 8];
            __builtin_amdgcn_s_setprio(1);
            st0 = __builtin_amdgcn_mfma_f32_32x32x16_bf16(
                kf0, qf[ds], st0, 0, 0, 0);
            st1 = __builtin_amdgcn_mfma_f32_32x32x16_bf16(
                kf1, qf[ds], st1, 0, 0, 0);
            __builtin_amdgcn_s_setprio(0);
        }

        // ---- online softmax (one query per lane) ------------------------
        // key for st{kr}[reg]: kr*32 + (reg&3) + 8*(reg>>2) + 4*hi
        // mask bit for (s=reg>>2, r=reg&3): position s*8 + hi*4 + r of word kr
        const uint2 mm = *(const uint2*)&Mt[cur][(w * 32 + l31) * 2];
        float rmax = -INFINITY;
        #pragma unroll
        for (int kr = 0; kr < 2; ++kr) {
            const unsigned w32 = kr ? mm.y : mm.x;
            #pragma unroll
            for (int s = 0; s < 4; ++s) {
                const unsigned nib = (w32 >> (s * 8 + hi * 4)) & 0xFu;
                #pragma unroll
                for (int r = 0; r < 4; ++r) {
                    float x = kr ? st1[s * 4 + r] : st0[s * 4 + r];
                    x = ((nib >> r) & 1u) ? x : -INFINITY;
                    if (kr) st1[s * 4 + r] = x; else st0[s * 4 + r] = x;
                    rmax = fmaxf(rmax, x);
                }
            }
        }
        rmax = fmaxf(rmax, __shfl_xor(rmax, 32));
        // T13 defer-max: skip rescale unless max grew by > 8 (exp2 domain)
        if (__any(rmax > m_run + 8.f)) {
            const float mnew  = fmaxf(m_run, rmax);
            const float alpha = __builtin_amdgcn_exp2f(
                m_run - fmaxf(mnew, -1e30f));     // clamp: -INF-(-INF) NaN guard
            l_run *= alpha;
            #pragma unroll
            for (int db = 0; db < 2; ++db)
                #pragma unroll
                for (int i = 0; i < 16; ++i) ot[db][i] *= alpha;
            m_run = mnew;
        }
        const float msafe = fmaxf(m_run, -1e30f);
        float psum = 0.f;
        #pragma unroll
        for (int kr = 0; kr < 2; ++kr)
            #pragma unroll
            for (int i = 0; i < 16; ++i) {
                const float p = __builtin_amdgcn_exp2f(
                    (kr ? st1[i] : st0[i]) - msafe);
                if (kr) st1[i] = p; else st0[i] = p;
                psum += p;
            }
        psum += __shfl_xor(psum, 32);
        l_run += psum;

        // ---- O^T += V^T·P^T : P^T frag via cvt_pk + shfl_xor(32) --------
        // kstep ks (16 keys ks*16..+15): kr = ks>>1, sA = 2*(ks&1).
        // Lane needs, for its dest half hi: s-quad (sA+hi) from BOTH src
        // halves — words 0,1 from src half 0; words 2,3 from src half 1.
        // cLo = own s=sA quad packed; cHi = own s=sA+1 quad packed;
        // x* = partner half's (lane^32) values. Select on DEST side.
        #pragma unroll
        for (int ks = 0; ks < 4; ++ks) {
            const int sA = (ks & 1) * 2;
            short8 vf0 = *(const short8*)
                &Vs[cur][(l31) * 64 + ((ks * 2 + hi) ^ swz) * 8];
            short8 vf1 = *(const short8*)
                &Vs[cur][(32 + l31) * 64 + ((ks * 2 + hi) ^ swz) * 8];
            unsigned cLo0, cLo1, cHi0, cHi1;
            if (ks >> 1) {
                cLo0 = cvt_pk_bf16(st1[sA*4+0], st1[sA*4+1]);
                cLo1 = cvt_pk_bf16(st1[sA*4+2], st1[sA*4+3]);
                cHi0 = cvt_pk_bf16(st1[sA*4+4], st1[sA*4+5]);
                cHi1 = cvt_pk_bf16(st1[sA*4+6], st1[sA*4+7]);
            } else {
                cLo0 = cvt_pk_bf16(st0[sA*4+0], st0[sA*4+1]);
                cLo1 = cvt_pk_bf16(st0[sA*4+2], st0[sA*4+3]);
                cHi0 = cvt_pk_bf16(st0[sA*4+4], st0[sA*4+5]);
                cHi1 = cvt_pk_bf16(st0[sA*4+6], st0[sA*4+7]);
            }
            const int xLo0 = __shfl_xor((int)cLo0, 32);
            const int xLo1 = __shfl_xor((int)cLo1, 32);
            const int xHi0 = __shfl_xor((int)cHi0, 32);
            const int xHi1 = __shfl_xor((int)cHi1, 32);
            i32x4 t;
            t.x = hi ? xHi0 : (int)cLo0;   // keys +0,1 (src half 0)
            t.y = hi ? xHi1 : (int)cLo1;   // keys +2,3 (src half 0)
            t.z = hi ? (int)cHi0 : xLo0;   // keys +4,5 (src half 1)
            t.w = hi ? (int)cHi1 : xLo1;   // keys +6,7 (src half 1)
            const short8 pf = *reinterpret_cast<short8*>(&t);
            __builtin_amdgcn_s_setprio(1);
            ot[0] = __builtin_amdgcn_mfma_f32_32x32x16_bf16(
                vf0, pf, ot[0], 0, 0, 0);
            ot[1] = __builtin_amdgcn_mfma_f32_32x32x16_bf16(
                vf1, pf, ot[1], 0, 0, 0);
            __builtin_amdgcn_s_setprio(0);
        }

        // one barrier/tile: drains next tile's loads and publishes
        // "all waves done reading buffer cur"
        __syncthreads();
    }

    // ---- epilogue: normalize, store ctx as bf16 [B,L,D] -----------------
    // ot[db][reg] = O^T[d = db*32 + (reg&3) + 8*(reg>>2) + 4*hi][q]
    const float rinv = (l_run > 0.f) ? (1.f / l_run) : 0.f;
    const size_t base = ((size_t)(b * L_ + q)) * D_ + h * 64;
    #pragma unroll
    for (int db = 0; db < 2; ++db)
        #pragma unroll
        for (int s = 0; s < 4; ++s) {
            ushort4 o;
            o.x = f2bf(ot[db][s * 4 + 0] * rinv);
            o.y = f2bf(ot[db][s * 4 + 1] * rinv);
            o.z = f2bf(ot[db][s * 4 + 2] * rinv);
            o.w = f2bf(ot[db][s * 4 + 3] * rinv);
            *(ushort4*)&Cb[base + db * 32 + s * 8 + hi * 4] = o;
        }
}

// ---------------------------------------------------------------------------
extern "C" void kernel_launch(void* const* d_in, const int* in_sizes, int n_in,
                              void* d_out, int out_size, void* d_ws, size_t ws_size,
                              hipStream_t stream)
{
    const float* q    = (const float*)d_in[0];
    const float* k    = (const float*)d_in[1];
    const float* v    = (const float*)d_in[2];
    const int*   mask = (const int*)d_in[3];
    const float* WQ   = (const float*)d_in[4];
    const float* bQ   = (const float*)d_in[5];
    const float* WK   = (const float*)d_in[6];
    const float* bK   = (const float*)d_in[7];
    const float* WV   = (const float*)d_in[8];
    const float* bV   = (const float*)d_in[9];
    const float* WO   = (const float*)d_in[10];
    const float* bO   = (const float*)d_in[11];
    float* out = (float*)d_out;

    const size_t NTOK = (size_t)B_ * L_;        // 8192

    // ws map (128 MiB): 8 x 16MB bf16 zones
    char* W = (char*)d_ws;
    unsigned short* qin = (unsigned short*)(W);                        // 16MB
    unsigned short* kin = (unsigned short*)(W + ((size_t)16  << 20));  // 16MB
    unsigned short* vin = (unsigned short*)(W + ((size_t)32  << 20));  // 16MB
    unsigned short* qbf = (unsigned short*)(W + ((size_t)48  << 20));  // 16MB
    unsigned short* kbf = (unsigned short*)(W + ((size_t)64  << 20));  // 16MB
    unsigned short* vbf = (unsigned short*)(W + ((size_t)80  << 20));  // 16MB
    unsigned short* vtb = (unsigned short*)(W + ((size_t)96  << 20));  // 16MB
    unsigned short* cb  = (unsigned short*)(W + ((size_t)112 << 20));  // 16MB
    // WTo reuses vin zone (dead after the fused QKV GEMM); must live in ws,
    // NOT d_out, because the final GEMM writes out over all of d_out.
    unsigned short* WTo = vin;

    // d_out as scratch until final GEMM (all dead before the out-write):
    unsigned int*   mbt32 = (unsigned int*)d_out;                            // 2MB
    unsigned short* WTq = (unsigned short*)((char*)d_out + ((size_t)2 << 20));
    unsigned short* WTk = (unsigned short*)((char*)d_out + ((size_t)4 << 20));
    unsigned short* WTv = (unsigned short*)((char*)d_out + ((size_t)6 << 20));

    pack_mask32_kernel<<<(B_ * L_ * L_) / 256, 256, 0, stream>>>(mask, mbt32);

    const int cvtg = (int)(NTOK * D_ / (256 * 8));   // 4096
    cvt3_bf16_kernel<<<dim3(cvtg, 3), 256, 0, stream>>>(q, k, v, qin, kin, vin);

    trans3_bf16_kernel<<<dim3(32, 32, 3), 256, 0, stream>>>(
        WQ, WK, WV, WTq, WTk, WTv);

    // Projections, bf16 out, one launch. Q gets scale*log2e folded in.
    const float qscale = 0.125f * 1.44269504088896340736f;
    dim3 ggrd3(D_ / 128, NTOK / 128, 3);        // (8, 64, 3) = 1536 wgs
    gemm3_mfma_kernel<<<ggrd3, 256, 0, stream>>>(
        qin, kin, vin, WTq, WTk, WTv, bQ, bK, bV, qbf, kbf, vbf, qscale);

    // WO transpose into vin zone (dead now); V transpose to [B,H,HD,L]
    transpose_bf16_kernel<<<dim3(32, 32), 256, 0, stream>>>(WO, WTo);
    vtrans_bf16_kernel<<<dim3(L_ / 64, H_, B_), 256, 0, stream>>>(vbf, vtb);

    attn_mfma_kernel<<<dim3(1024), 256, 0, stream>>>(qbf, kbf, vtb, mbt32, cb);

    dim3 ggrd(D_ / 128, NTOK / 128);            // (8, 64)
    gemm_mfma_kernel<<<ggrd, 256, 0, stream>>>(cb, WTo, bO, out, (int)NTOK, D_, D_);
}